// Round 4
// baseline (517.064 us; speedup 1.0000x reference)
//
#include <hip/hip_runtime.h>
#include <hip/hip_bf16.h>

// Color_Attention: transposed (channel) attention.
//   Z = [I; C] (384 x 16384 bf16, per batch, tiled+swizzled, stored in d_out as scratch)
//   Z*Z^T upper triangle = { G_ii, G_ic, G_cc }  (one symmetric gram kernel)
//   A_pre = Wq*G_ci*Wk^T ; nq = diag(Wq*G_cc*Wq^T); nk = diag(Wk*G_ii*Wk^T)
//   attn = softmax over head-diagonal 24x24 blocks of A_pre/(nq*nk)
//   P = Wo * blockdiag(attn) * Wv ; out = P @ input

typedef __attribute__((ext_vector_type(4))) float f32x4;
typedef __attribute__((ext_vector_type(8))) short short8;

#define MFMA16(a, b, c) __builtin_amdgcn_mfma_f32_16x16x32_bf16((a), (b), (c), 0, 0, 0)

__device__ __forceinline__ unsigned int pack_rne(float a, float b) {
  unsigned int ua = __float_as_uint(a), ub = __float_as_uint(b);
  ua += 0x7fffu + ((ua >> 16) & 1u);
  ub += 0x7fffu + ((ub >> 16) & 1u);
  return (ua >> 16) | (ub & 0xffff0000u);
}
__device__ __forceinline__ unsigned short bf16u_rne(float x) {
  unsigned int u = __float_as_uint(x);
  u += 0x7fffu + ((u >> 16) & 1u);
  return (unsigned short)(u >> 16);
}
union S8U { short8 s; unsigned int u[4]; };
__device__ __forceinline__ short8 load_cvt8(const float* p) {
  f32x4 x = *(const f32x4*)p;
  f32x4 y = *(const f32x4*)(p + 4);
  S8U r;
  r.u[0] = pack_rne(x[0], x[1]);
  r.u[1] = pack_rne(x[2], x[3]);
  r.u[2] = pack_rne(y[0], y[1]);
  r.u[3] = pack_rne(y[2], y[3]);
  return r.s;
}

#define HW 16384
#define CDIM 192
#define NB 8
#define TILE_B 49152  // 384 rows * 128 B

// ---------------- Kernel A: convert fp32 -> swizzled bf16 Z tiles ------------
// Z tile (b, kc): rows 0..191 = input channels, 192..383 = color channels,
// row r = 64 bf16 (128B), byte cb stored at cb ^ ((r&7)<<4)  (b128-frag-read swizzle).
// Also (block x==256, b==0): Wv transpose -> WvT bf16.
__global__ __launch_bounds__(256) void convert_k(const float* __restrict__ input,
                                                 const float* __restrict__ color,
                                                 const float* __restrict__ Wv,
                                                 unsigned short* __restrict__ WvT,
                                                 char* __restrict__ zbf) {
  const int kc = blockIdx.x, b = blockIdx.y;
  const int t = threadIdx.x;
  if (kc == 256) {
    if (b == 0) {
      for (int idx = t; idx < CDIM * CDIM; idx += 256) {
        int j = idx / CDIM, cp = idx % CDIM;
        WvT[idx] = bf16u_rne(Wv[(size_t)cp * CDIM + j]);
      }
    }
    return;
  }
  char* zt = zbf + ((size_t)b * 256 + kc) * TILE_B;
  const int srow = t >> 4;             // 0..15
  const int c4 = (t & 15) * 4;         // f32 col
  const int cb = c4 * 2;               // byte col
  const int sw = (srow & 7) << 4;
  const float* ib = input + (size_t)b * CDIM * HW + (size_t)kc * 64 + c4;
  const float* cp = color + (size_t)b * CDIM * HW + (size_t)kc * 64 + c4;
#pragma unroll
  for (int r = 0; r < 12; ++r) {
    const int row = r * 16 + srow;
    f32x4 v = *(const f32x4*)(ib + (size_t)row * HW);
    unsigned long long p0 = (unsigned long long)pack_rne(v[0], v[1]) |
                            ((unsigned long long)pack_rne(v[2], v[3]) << 32);
    *(unsigned long long*)(zt + row * 128 + (cb ^ sw)) = p0;
    f32x4 w = *(const f32x4*)(cp + (size_t)row * HW);
    unsigned long long p1 = (unsigned long long)pack_rne(w[0], w[1]) |
                            ((unsigned long long)pack_rne(w[2], w[3]) << 32);
    *(unsigned long long*)(zt + (192 + row) * 128 + (cb ^ sw)) = p1;
  }
}

// ---------------- Kernel B: gram Z*Z^T (upper triangle) ----------------------
__device__ __forceinline__ short8 zfrag(const char* buf, int row, int ks, int lg) {
  return *(const short8*)(buf + row * 128 + ((ks * 64 + lg * 16) ^ ((row & 7) << 4)));
}

__device__ __forceinline__ void stage48(const char* gsrc, char* ldst, int wave, int lane) {
#pragma unroll
  for (int i = 0; i < 6; ++i) {
    const int off = (wave * 6 + i) * 1024;
    __builtin_amdgcn_global_load_lds(
        (const __attribute__((address_space(1))) void*)(gsrc + off + lane * 16),
        (__attribute__((address_space(3))) void*)(ldst + off), 16, 0, 0);
  }
}

// waves 0..3: G_ic = I*C^T. A row-tiles 3w..3w+2 (I), B col-tiles 0..11 (C).
__device__ __forceinline__ void gic_step(const char* buf, int w, f32x4 (&acc)[39],
                                         int l15, int lg) {
#pragma unroll
  for (int ks = 0; ks < 2; ++ks) {
    short8 a[3];
#pragma unroll
    for (int tt = 0; tt < 3; ++tt) a[tt] = zfrag(buf, (w * 3 + tt) * 16 + l15, ks, lg);
#pragma unroll
    for (int tj = 0; tj < 12; ++tj) {
      short8 bf = zfrag(buf, 192 + tj * 16 + l15, ks, lg);
#pragma unroll
      for (int tt = 0; tt < 3; ++tt) acc[tt * 12 + tj] = MFMA16(a[tt], bf, acc[tt * 12 + tj]);
    }
  }
}

// sym waves: pairs (R,11-R) for R in {R0,R1,R2}; 13 tiles per pair.
template <int R0, int R1, int R2>
__device__ __forceinline__ void sym_step(const char* buf, int zbase, f32x4 (&acc)[39],
                                         int l15, int lg) {
#pragma unroll
  for (int ks = 0; ks < 2; ++ks) {
    short8 bfr[12];
#pragma unroll
    for (int tj = R0; tj < 12; ++tj) bfr[tj] = zfrag(buf, zbase + tj * 16 + l15, ks, lg);
#pragma unroll
    for (int p = 0; p < 3; ++p) {
      const int R = (p == 0) ? R0 : ((p == 1) ? R1 : R2);
      short8 aT = zfrag(buf, zbase + R * 16 + l15, ks, lg);
      short8 aB = zfrag(buf, zbase + (11 - R) * 16 + l15, ks, lg);
#pragma unroll
      for (int tj = 0; tj < 12; ++tj) {
        if (tj >= R) acc[p * 13 + (tj - R)] = MFMA16(aT, bfr[tj], acc[p * 13 + (tj - R)]);
        if (tj >= 11 - R) {
          const int s = p * 13 + (12 - R) + (tj - (11 - R));
          acc[s] = MFMA16(aB, bfr[tj], acc[s]);
        }
      }
    }
  }
}

template <int R0, int R1, int R2>
__device__ __forceinline__ void flush_sym(float* __restrict__ Gs, f32x4 (&acc)[39],
                                          int l15, int lg) {
#pragma unroll
  for (int p = 0; p < 3; ++p) {
    const int R = (p == 0) ? R0 : ((p == 1) ? R1 : R2);
#pragma unroll
    for (int tj = 0; tj < 12; ++tj) {
      if (tj >= R) {
        const f32x4 v = acc[p * 13 + (tj - R)];
        const int m0 = R * 16 + lg * 4, n = tj * 16 + l15;
#pragma unroll
        for (int r = 0; r < 4; ++r) atomicAdd(&Gs[(size_t)(m0 + r) * CDIM + n], v[r]);
        if (tj > R) {
#pragma unroll
          for (int r = 0; r < 4; ++r) atomicAdd(&Gs[(size_t)n * CDIM + (m0 + r)], v[r]);
        }
      }
      if (tj >= 11 - R) {
        const f32x4 v = acc[p * 13 + (12 - R) + (tj - (11 - R))];
        const int m0 = (11 - R) * 16 + lg * 4, n = tj * 16 + l15;
#pragma unroll
        for (int r = 0; r < 4; ++r) atomicAdd(&Gs[(size_t)(m0 + r) * CDIM + n], v[r]);
        if (tj > 11 - R) {
#pragma unroll
          for (int r = 0; r < 4; ++r) atomicAdd(&Gs[(size_t)n * CDIM + (m0 + r)], v[r]);
        }
      }
    }
  }
}

// grid (32, 8), 512 threads, 8 waves, LDS 2x48KB double buffer.
__global__ __launch_bounds__(512, 2) void gram2_k(const char* __restrict__ zbf,
                                                  float* __restrict__ G) {
  __shared__ __align__(16) char lds[2][TILE_B];
  const int tid = threadIdx.x, wave = tid >> 6, lane = tid & 63;
  const int l15 = lane & 15, lg = (lane >> 4) & 3;
  const int strip = blockIdx.x, b = blockIdx.y;
  const char* ztb = zbf + ((size_t)b * 256 + (size_t)strip * 8) * TILE_B;

  f32x4 acc[39];
#pragma unroll
  for (int i = 0; i < 39; ++i) acc[i] = (f32x4){0.f, 0.f, 0.f, 0.f};

  stage48(ztb, lds[0], wave, lane);
#pragma unroll 1
  for (int c = 0; c < 7; ++c) {
    stage48(ztb + (size_t)(c + 1) * TILE_B, lds[(c + 1) & 1], wave, lane);
    asm volatile("s_waitcnt vmcnt(6)" ::: "memory");
    __builtin_amdgcn_sched_barrier(0);
    __builtin_amdgcn_s_barrier();
    const char* buf = lds[c & 1];
    if (wave < 4) gic_step(buf, wave, acc, l15, lg);
    else if (wave == 4) sym_step<0, 1, 2>(buf, 192, acc, l15, lg);
    else if (wave == 5) sym_step<3, 4, 5>(buf, 192, acc, l15, lg);
    else if (wave == 6) sym_step<0, 1, 2>(buf, 0, acc, l15, lg);
    else sym_step<3, 4, 5>(buf, 0, acc, l15, lg);
    asm volatile("s_waitcnt lgkmcnt(0)" ::: "memory");
    __builtin_amdgcn_sched_barrier(0);
    __builtin_amdgcn_s_barrier();
  }
  asm volatile("s_waitcnt vmcnt(0)" ::: "memory");
  __builtin_amdgcn_sched_barrier(0);
  __builtin_amdgcn_s_barrier();
  {
    const char* buf = lds[1];
    if (wave < 4) gic_step(buf, wave, acc, l15, lg);
    else if (wave == 4) sym_step<0, 1, 2>(buf, 192, acc, l15, lg);
    else if (wave == 5) sym_step<3, 4, 5>(buf, 192, acc, l15, lg);
    else if (wave == 6) sym_step<0, 1, 2>(buf, 0, acc, l15, lg);
    else sym_step<3, 4, 5>(buf, 0, acc, l15, lg);
  }

  if (wave < 4) {
    float* G0 = G + (size_t)b * CDIM * CDIM;
#pragma unroll
    for (int tt = 0; tt < 3; ++tt) {
      const int m0 = (wave * 3 + tt) * 16 + lg * 4;
#pragma unroll
      for (int tj = 0; tj < 12; ++tj) {
        const int n = tj * 16 + l15;
        const f32x4 v = acc[tt * 12 + tj];
#pragma unroll
        for (int r = 0; r < 4; ++r) atomicAdd(&G0[(size_t)(m0 + r) * CDIM + n], v[r]);
      }
    }
  } else {
    float* Gs = G + ((size_t)((wave < 6) ? (NB + b) : (2 * NB + b))) * (CDIM * CDIM);
    if (wave == 4 || wave == 6) flush_sym<0, 1, 2>(Gs, acc, l15, lg);
    else flush_sym<3, 4, 5>(Gs, acc, l15, lg);
  }
}

// ---------------- Kernel 2a: A_pre (type0), nq (type1), nk (type2) ----------
__global__ __launch_bounds__(256) void k2a(const float* __restrict__ G,
                                           const float* __restrict__ Wq,
                                           const float* __restrict__ Wk,
                                           float* __restrict__ A_pre,
                                           float* __restrict__ nqk) {
  const int b = blockIdx.x, type = blockIdx.y;
  __shared__ __align__(16) unsigned short Hs[192][200];
  const int tid = threadIdx.x, wave = tid >> 6, lane = tid & 63;
  const int l15 = lane & 15, lg = lane >> 4, row0 = wave * 48;
  const float* W1 = (type == 2) ? Wk : Wq;
  const float* Gm = G + ((size_t)type * NB + b) * (CDIM * CDIM);

  f32x4 acc[3][12];
#pragma unroll
  for (int t = 0; t < 3; t++)
#pragma unroll
    for (int j = 0; j < 12; j++) acc[t][j] = (f32x4){0.f, 0.f, 0.f, 0.f};

  for (int ks = 0; ks < 192; ks += 32) {
    short8 afr[3];
#pragma unroll
    for (int t = 0; t < 3; t++)
      afr[t] = load_cvt8(W1 + (size_t)(row0 + t * 16 + l15) * CDIM + ks + lg * 8);
#pragma unroll
    for (int tj = 0; tj < 12; tj++) {
      short8 bfr = load_cvt8(Gm + (size_t)(tj * 16 + l15) * CDIM + ks + lg * 8);
#pragma unroll
      for (int t = 0; t < 3; t++) acc[t][tj] = MFMA16(afr[t], bfr, acc[t][tj]);
    }
  }
#pragma unroll
  for (int t = 0; t < 3; t++)
#pragma unroll
    for (int tj = 0; tj < 12; tj++)
#pragma unroll
      for (int r = 0; r < 4; r++)
        Hs[row0 + t * 16 + lg * 4 + r][tj * 16 + l15] = bf16u_rne(acc[t][tj][r]);
  __syncthreads();

  if (type == 0) {
    f32x4 a2[3][12];
#pragma unroll
    for (int t = 0; t < 3; t++)
#pragma unroll
      for (int j = 0; j < 12; j++) a2[t][j] = (f32x4){0.f, 0.f, 0.f, 0.f};
    for (int ks = 0; ks < 192; ks += 32) {
      short8 afr[3];
#pragma unroll
      for (int t = 0; t < 3; t++)
        afr[t] = *(const short8*)&Hs[row0 + t * 16 + l15][ks + lg * 8];
#pragma unroll
      for (int tj = 0; tj < 12; tj++) {
        short8 bfr = load_cvt8(Wk + (size_t)(tj * 16 + l15) * CDIM + ks + lg * 8);
#pragma unroll
        for (int t = 0; t < 3; t++) a2[t][tj] = MFMA16(afr[t], bfr, a2[t][tj]);
      }
    }
    float* Ab = A_pre + (size_t)b * CDIM * CDIM;
#pragma unroll
    for (int t = 0; t < 3; t++)
#pragma unroll
      for (int tj = 0; tj < 12; tj++)
#pragma unroll
        for (int r = 0; r < 4; r++)
          Ab[(size_t)(row0 + t * 16 + lg * 4 + r) * CDIM + tj * 16 + l15] = a2[t][tj][r];
  } else {
    f32x4 a2[3];
#pragma unroll
    for (int t = 0; t < 3; t++) a2[t] = (f32x4){0.f, 0.f, 0.f, 0.f};
    for (int ks = 0; ks < 192; ks += 32) {
#pragma unroll
      for (int t = 0; t < 3; t++) {
        short8 afr = *(const short8*)&Hs[row0 + t * 16 + l15][ks + lg * 8];
        short8 bfr = load_cvt8(W1 + (size_t)(row0 + t * 16 + l15) * CDIM + ks + lg * 8);
        a2[t] = MFMA16(afr, bfr, a2[t]);
      }
    }
    float* dst = nqk + ((size_t)(type - 1) * NB + b) * CDIM;
#pragma unroll
    for (int t = 0; t < 3; t++)
#pragma unroll
      for (int r = 0; r < 4; r++)
        if (lg * 4 + r == l15) dst[row0 + t * 16 + l15] = a2[t][r];
  }
}

// ---------------- Kernel 2b: per-head softmax ----------------
__global__ void k2b(const float* __restrict__ A_pre, const float* __restrict__ nqk,
                    float* __restrict__ attnw) {
  const int b = blockIdx.x, tid = threadIdx.x;
  const int h = tid >> 5, r = tid & 31;
  if (r >= 24) return;
  const float* Ab = A_pre + (size_t)b * CDIM * CDIM;
  const float* nq = nqk + (size_t)b * CDIM;
  const float* nk = nqk + (size_t)(NB + b) * CDIM;
  const int c = h * 24 + r;
  const float qn = rsqrtf(fmaxf(nq[c], 1e-24f));
  float e[24];
  float mx = -1e30f;
#pragma unroll
  for (int d = 0; d < 24; d++) {
    float kn = rsqrtf(fmaxf(nk[h * 24 + d], 1e-24f));
    float l = Ab[(size_t)c * CDIM + h * 24 + d] * qn * kn;
    e[d] = l;
    mx = fmaxf(mx, l);
  }
  float s = 0.f;
#pragma unroll
  for (int d = 0; d < 24; d++) {
    float x = __expf(e[d] - mx);
    e[d] = x;
    s += x;
  }
  const float inv = 1.0f / s;
  float* dst = attnw + (((size_t)b * NB + h) * 24 + r) * 24;
#pragma unroll
  for (int d = 0; d < 24; d++) dst[d] = e[d] * inv;
}

// ---------------- Kernel 3: P = Wo * blockdiag(attn) * Wv  (bf16 out) -------
__global__ __launch_bounds__(256) void k3(const float* __restrict__ attnw,
                                          const float* __restrict__ Wo,
                                          const unsigned short* __restrict__ WvT,
                                          unsigned short* __restrict__ Pbf) {
  const int b = blockIdx.x;
  __shared__ __align__(16) unsigned short AT[192][200];
  __shared__ __align__(16) unsigned short Ms[192][200];
  const int tid = threadIdx.x, wave = tid >> 6, lane = tid & 63;
  const int l15 = lane & 15, lg = lane >> 4, row0 = wave * 48;

  unsigned int* ATu = (unsigned int*)&AT[0][0];
  for (int i = tid; i < 192 * 100; i += 256) ATu[i] = 0u;
  __syncthreads();
  const float* at = attnw + (size_t)b * NB * 24 * 24;
  for (int i = tid; i < 4608; i += 256) {
    int h = i / 576, rem = i % 576, c = rem / 24, d = rem % 24;
    AT[h * 24 + d][h * 24 + c] = bf16u_rne(at[(h * 24 + c) * 24 + d]);
  }
  __syncthreads();

  f32x4 acc[3][12];
#pragma unroll
  for (int t = 0; t < 3; t++)
#pragma unroll
    for (int j = 0; j < 12; j++) acc[t][j] = (f32x4){0.f, 0.f, 0.f, 0.f};
  for (int ks = 0; ks < 192; ks += 32) {
    short8 afr[3];
#pragma unroll
    for (int t = 0; t < 3; t++)
      afr[t] = load_cvt8(Wo + (size_t)(row0 + t * 16 + l15) * CDIM + ks + lg * 8);
#pragma unroll
    for (int tj = 0; tj < 12; tj++) {
      short8 bfr = *(const short8*)&AT[tj * 16 + l15][ks + lg * 8];
#pragma unroll
      for (int t = 0; t < 3; t++) acc[t][tj] = MFMA16(afr[t], bfr, acc[t][tj]);
    }
  }
#pragma unroll
  for (int t = 0; t < 3; t++)
#pragma unroll
    for (int tj = 0; tj < 12; tj++)
#pragma unroll
      for (int r = 0; r < 4; r++)
        Ms[row0 + t * 16 + lg * 4 + r][tj * 16 + l15] = bf16u_rne(acc[t][tj][r]);
  __syncthreads();

  f32x4 a2[3][12];
#pragma unroll
  for (int t = 0; t < 3; t++)
#pragma unroll
    for (int j = 0; j < 12; j++) a2[t][j] = (f32x4){0.f, 0.f, 0.f, 0.f};
  for (int ks = 0; ks < 192; ks += 32) {
    short8 afr[3];
#pragma unroll
    for (int t = 0; t < 3; t++)
      afr[t] = *(const short8*)&Ms[row0 + t * 16 + l15][ks + lg * 8];
#pragma unroll
    for (int tj = 0; tj < 12; tj++) {
      short8 bfr = *(const short8*)(WvT + (size_t)(tj * 16 + l15) * CDIM + ks + lg * 8);
#pragma unroll
      for (int t = 0; t < 3; t++) a2[t][tj] = MFMA16(afr[t], bfr, a2[t][tj]);
    }
  }
  unsigned short* Pb = Pbf + (size_t)b * CDIM * CDIM;
#pragma unroll
  for (int t = 0; t < 3; t++)
#pragma unroll
    for (int tj = 0; tj < 12; tj++)
#pragma unroll
      for (int r = 0; r < 4; r++)
        Pb[(size_t)(row0 + t * 16 + lg * 4 + r) * CDIM + tj * 16 + l15] = bf16u_rne(a2[t][tj][r]);
}

// ---------------- Kernel D: out = P @ input  ----------------
// BsT[n][k] bf16, 384B rows, XOR swizzle ((n&7)<<4): b128 fragment reads.
__global__ __launch_bounds__(256) void kD(const unsigned short* __restrict__ Pbf,
                                          const float* __restrict__ input,
                                          float* __restrict__ out) {
  const int nchunk = blockIdx.x, b = blockIdx.y;
  const int n0 = nchunk * 128;
  __shared__ __align__(16) char BsT[128 * 384];
  const int tid = threadIdx.x, wave = tid >> 6, lane = tid & 63;
  const int l15 = lane & 15, lg = lane >> 4, row0 = wave * 48;

  {
    const int n4 = (tid & 31) * 4;
    const int kb0 = (tid >> 5) * 4;
    const float* src = input + (size_t)b * CDIM * HW + n0 + n4;
#pragma unroll
    for (int rnd = 0; rnd < 6; ++rnd) {
      const int kb = kb0 + rnd * 32;
      f32x4 v0 = *(const f32x4*)(src + (size_t)(kb + 0) * HW);
      f32x4 v1 = *(const f32x4*)(src + (size_t)(kb + 1) * HW);
      f32x4 v2 = *(const f32x4*)(src + (size_t)(kb + 2) * HW);
      f32x4 v3 = *(const f32x4*)(src + (size_t)(kb + 3) * HW);
#pragma unroll
      for (int i = 0; i < 4; ++i) {
        const int n = n4 + i;
        unsigned long long pk = (unsigned long long)pack_rne(v0[i], v1[i]) |
                                ((unsigned long long)pack_rne(v2[i], v3[i]) << 32);
        *(unsigned long long*)(BsT + n * 384 + ((kb * 2) ^ ((n & 7) << 4))) = pk;
      }
    }
  }
  __syncthreads();

  f32x4 acc[3][8];
#pragma unroll
  for (int t = 0; t < 3; t++)
#pragma unroll
    for (int j = 0; j < 8; j++) acc[t][j] = (f32x4){0.f, 0.f, 0.f, 0.f};

  const unsigned short* Pb = Pbf + (size_t)b * CDIM * CDIM;
#pragma unroll 2
  for (int ks = 0; ks < 6; ks++) {
    short8 afr[3];
#pragma unroll
    for (int t = 0; t < 3; t++)
      afr[t] = *(const short8*)(Pb + (size_t)(row0 + t * 16 + l15) * CDIM + ks * 32 + lg * 8);
#pragma unroll
    for (int tn = 0; tn < 8; tn++) {
      const int n = tn * 16 + l15;
      short8 bfr = *(const short8*)(BsT + n * 384 + ((ks * 64 + lg * 16) ^ ((n & 7) << 4)));
#pragma unroll
      for (int t = 0; t < 3; t++) acc[t][tn] = MFMA16(afr[t], bfr, acc[t][tn]);
    }
  }
  float* ob = out + (size_t)b * CDIM * HW + n0;
#pragma unroll
  for (int t = 0; t < 3; t++)
#pragma unroll
    for (int tn = 0; tn < 8; tn++)
#pragma unroll
      for (int r = 0; r < 4; r++) {
        const int m = row0 + t * 16 + lg * 4 + r;
        ob[(size_t)m * HW + tn * 16 + l15] = acc[t][tn][r];
      }
}

// ---------------- launch ----------------
extern "C" void kernel_launch(void* const* d_in, const int* in_sizes, int n_in,
                              void* d_out, int out_size, void* d_ws, size_t ws_size,
                              hipStream_t stream) {
  const float* input = (const float*)d_in[0];
  const float* color = (const float*)d_in[1];
  const float* Wq = (const float*)d_in[2];
  const float* Wk = (const float*)d_in[3];
  const float* Wv = (const float*)d_in[4];
  const float* Wo = (const float*)d_in[5];
  float* out = (float*)d_out;
  char* ws = (char*)d_ws;

  const size_t OFF_G = 0;                        // 3*8*192*192*4 = 3538944
  const size_t OFF_APRE = 3538944;               // 8*192*192*4  = 1179648
  const size_t OFF_NQK = OFF_APRE + 1179648;     // 2*8*192*4    = 12288
  const size_t OFF_ATT = OFF_NQK + 12288;        // 8*8*24*24*4  = 147456
  const size_t OFF_WVT = OFF_ATT + 147456;       // 192*192*2    = 73728
  const size_t OFF_PBF = OFF_WVT + 73728;        // 8*192*192*2  = 589824

  float* G = (float*)(ws + OFF_G);
  float* A_pre = (float*)(ws + OFF_APRE);
  float* nqk = (float*)(ws + OFF_NQK);
  float* attnw = (float*)(ws + OFF_ATT);
  unsigned short* WvT = (unsigned short*)(ws + OFF_WVT);
  unsigned short* Pbf = (unsigned short*)(ws + OFF_PBF);

  // Z (bf16, swizzled tiles) lives in d_out as scratch; kD overwrites it last.
  char* zbf = (char*)d_out;

  hipMemsetAsync(G, 0, 3 * NB * CDIM * CDIM * sizeof(float), stream);
  convert_k<<<dim3(257, NB), dim3(256), 0, stream>>>(input, color, Wv, WvT, zbf);
  gram2_k<<<dim3(32, NB), dim3(512), 0, stream>>>(zbf, G);
  k2a<<<dim3(NB, 3), dim3(256), 0, stream>>>(G, Wq, Wk, A_pre, nqk);
  k2b<<<dim3(NB), dim3(256), 0, stream>>>(A_pre, nqk, attnw);
  k3<<<dim3(NB), dim3(256), 0, stream>>>(attnw, Wo, WvT, Pbf);
  kD<<<dim3(HW / 128, NB), dim3(256), 0, stream>>>(Pbf, input, out);
}